// Round 11
// baseline (484.343 us; speedup 1.0000x reference)
//
#include <hip/hip_runtime.h>
#include <hip/hip_bf16.h>
#include <math.h>

typedef __attribute__((ext_vector_type(8))) short short8;
typedef __attribute__((ext_vector_type(4))) float floatx4;
typedef __hip_bfloat16 bf16;

#define LDSQ 40   // 128x128 core LDS stride: 80B rows -> free 2-way bank aliasing

__device__ __forceinline__ float sigmoidf_(float v) { return 1.f / (1.f + __expf(-v)); }
// tanh via single v_exp: 1 - 2/(e^{2v}+1). |abs err| ~1e-7; bf16 output tolerance huge.
__device__ __forceinline__ float tanhf_(float v) {
  float e = __expf(2.f * v);
  return 1.f - 2.f / (e + 1.f);
}

// ---------------------------------------------------------------------------
// 128x128-tile bf16 MFMA core (m97 shape): 256 thr = 4 waves (2x2), each wave
// a 64x64 quadrant = 4x4 fragments of v_mfma_f32_16x16x32_bf16 (64 acc VGPRs).
// BK=32; per K-step: stage A+B (reg->LDS), 8 ds_read_b128 + 16 MFMA per lane.
// AMODE 0: A bf16. AMODE 1: A fp32 truncation-packed to bf16 during staging
// (2 VALU / 2 elems, err <= 1 ulp bf16), zero-padded past kvalid.
// DUAL: K-loop spans two (A,Bt) pairs (validated pointer-switch pattern).
// ---------------------------------------------------------------------------
template<int AMODE, bool DUAL>
__device__ __forceinline__ void gemm128_core(
    const void* A0p, const void* A1p, int lda, int kvalid,
    const bf16* B0, const bf16* B1, int ldb, int ksteps,
    floatx4 acc[4][4], bf16* As, bf16* Bs)
{
  const int tid = threadIdx.x, lane = tid & 63, wave = tid >> 6;
  const int wm = wave >> 1, wn = wave & 1;
  const int srow = tid >> 1, sc = (tid & 1) * 16;   // staging: 128 rows x 2 halves of 16
  const size_t m0 = (size_t)blockIdx.x * 128;
  const size_t n0 = (size_t)blockIdx.y * 128;
  const int half = DUAL ? (ksteps >> 1) : ksteps;
  const int fr = lane & 15, kb = lane >> 4;

  #pragma unroll
  for (int i = 0; i < 4; ++i)
    #pragma unroll
    for (int j = 0; j < 4; ++j) acc[i][j] = {0.f, 0.f, 0.f, 0.f};

  for (int kt = 0; kt < ksteps; ++kt) {
    const bool second = DUAL && (kt >= half);
    const void* Ap = second ? A1p : A0p;
    const bf16* Bp = second ? B1 : B0;
    const int kbase = (second ? (kt - half) : kt) * 32 + sc;

    if (AMODE == 1) {
      const float* Af = (const float*)Ap + (m0 + srow) * (size_t)lda + kbase;
      unsigned u[16];
      if (kbase + 16 <= kvalid) {
        float4 q0 = *(const float4*)(Af);
        float4 q1 = *(const float4*)(Af + 4);
        float4 q2 = *(const float4*)(Af + 8);
        float4 q3 = *(const float4*)(Af + 12);
        u[0]=__float_as_uint(q0.x); u[1]=__float_as_uint(q0.y); u[2]=__float_as_uint(q0.z); u[3]=__float_as_uint(q0.w);
        u[4]=__float_as_uint(q1.x); u[5]=__float_as_uint(q1.y); u[6]=__float_as_uint(q1.z); u[7]=__float_as_uint(q1.w);
        u[8]=__float_as_uint(q2.x); u[9]=__float_as_uint(q2.y); u[10]=__float_as_uint(q2.z); u[11]=__float_as_uint(q2.w);
        u[12]=__float_as_uint(q3.x); u[13]=__float_as_uint(q3.y); u[14]=__float_as_uint(q3.z); u[15]=__float_as_uint(q3.w);
      } else {
        #pragma unroll
        for (int e = 0; e < 16; ++e)
          u[e] = (kbase + e < kvalid) ? __float_as_uint(Af[e]) : 0u;
      }
      uint4 p0, p1;   // truncation pack: lo16 = even elem, hi16 = odd elem
      p0.x = (u[1] & 0xFFFF0000u) | (u[0] >> 16);
      p0.y = (u[3] & 0xFFFF0000u) | (u[2] >> 16);
      p0.z = (u[5] & 0xFFFF0000u) | (u[4] >> 16);
      p0.w = (u[7] & 0xFFFF0000u) | (u[6] >> 16);
      p1.x = (u[9] & 0xFFFF0000u) | (u[8] >> 16);
      p1.y = (u[11] & 0xFFFF0000u) | (u[10] >> 16);
      p1.z = (u[13] & 0xFFFF0000u) | (u[12] >> 16);
      p1.w = (u[15] & 0xFFFF0000u) | (u[14] >> 16);
      *(uint4*)&As[srow * LDSQ + sc]     = p0;
      *(uint4*)&As[srow * LDSQ + sc + 8] = p1;
    } else {
      const bf16* Ab = (const bf16*)Ap + (m0 + srow) * (size_t)lda + kbase;
      *(short8*)&As[srow * LDSQ + sc]     = *(const short8*)Ab;
      *(short8*)&As[srow * LDSQ + sc + 8] = *(const short8*)(Ab + 8);
    }
    {
      const bf16* Bb = Bp + (n0 + srow) * (size_t)ldb + kbase;
      *(short8*)&Bs[srow * LDSQ + sc]     = *(const short8*)Bb;
      *(short8*)&Bs[srow * LDSQ + sc + 8] = *(const short8*)(Bb + 8);
    }
    __syncthreads();

    short8 a[4], b[4];
    #pragma unroll
    for (int i = 0; i < 4; ++i)
      a[i] = *(const short8*)&As[(wm * 64 + i * 16 + fr) * LDSQ + kb * 8];
    #pragma unroll
    for (int j = 0; j < 4; ++j)
      b[j] = *(const short8*)&Bs[(wn * 64 + j * 16 + fr) * LDSQ + kb * 8];
    #pragma unroll
    for (int i = 0; i < 4; ++i)
      #pragma unroll
      for (int j = 0; j < 4; ++j)
        acc[i][j] = __builtin_amdgcn_mfma_f32_16x16x32_bf16(a[i], b[j], acc[i][j], 0, 0, 0);
    __syncthreads();
  }
}

// C/D fragment element (verified m89/m91): col = lane&15, row = (lane>>4)*4 + reg
#define EPI128 \
  const int tid = threadIdx.x, lane = tid & 63, wave = tid >> 6; \
  const int wm = wave >> 1, wn = wave & 1; \
  const int m0 = blockIdx.x * 128, n0 = blockIdx.y * 128; \
  const int rq = lane >> 4, col = lane & 15; \
  (void)m0;

// ---- all weight transposes in one launch: dst[c][r]=src[r][c], pad r to dld
struct TransPack {
  const float* src[7];
  bf16* dst[7];
  int rows[7];
  int dld[7];
};
__global__ __launch_bounds__(256) void k_transpose_all(TransPack p) {
  const int w = blockIdx.y;                 // wave-uniform -> scalar kernarg loads
  const int dld = p.dld[w];
  int idx = blockIdx.x * 256 + threadIdx.x;
  if (idx >= 256 * dld) return;
  int c = idx / dld, r = idx - c * dld;
  float v = (r < p.rows[w]) ? p.src[w][(size_t)r * 256 + c] : 0.f;
  p.dst[w][idx] = __float2bfloat16(v);
}

// ---- GEMM1: h = tanh(x @ Wx + bx) -> scatter to center/neigh. 128x128 tile.
__global__ __launch_bounds__(256) void k_gemm1_128(
    const float* __restrict__ x, const bf16* __restrict__ WxT,
    const float* __restrict__ bx, bf16* __restrict__ center, bf16* __restrict__ neigh) {
  __shared__ bf16 As[128 * LDSQ], Bs[128 * LDSQ];
  floatx4 acc[4][4];
  gemm128_core<1, false>(x, nullptr, 300, 300, WxT, nullptr, 320, 10, acc, As, Bs);
  EPI128
  #pragma unroll
  for (int i = 0; i < 4; ++i)
    #pragma unroll
    for (int j = 0; j < 4; ++j) {
      int gc = n0 + wn * 64 + j * 16 + col;
      float bias = bx[gc];
      #pragma unroll
      for (int r = 0; r < 4; ++r) {
        int gm = m0 + wm * 64 + i * 16 + rq * 4 + r;
        float v = tanhf_(acc[i][j][r] + bias);
        int node = gm / 17, slot = gm - node * 17;
        bf16 bv = __float2bfloat16(v);
        if (slot == 0) center[(size_t)node * 256 + gc] = bv;
        else           neigh[((size_t)node * 16 + (slot - 1)) * 256 + gc] = bv;
      }
    }
}

// ---- attn: neigh @ Uh, fused masked softmax over K=16 + con reduce. 128x128.
// Each 16x16 C fragment = one node (16 neighbor rows = softmax axis) x 16 ch.
__global__ __launch_bounds__(256) void k_gemm_attn_128(
    const bf16* __restrict__ neigh, const bf16* __restrict__ UhT,
    const float* __restrict__ bu, const float* __restrict__ Ct,
    const int* __restrict__ cnts, bf16* __restrict__ con) {
  __shared__ bf16 As[128 * LDSQ], Bs[128 * LDSQ];
  floatx4 acc[4][4];
  gemm128_core<0, false>(neigh, nullptr, 256, 256, UhT, nullptr, 256, 8, acc, As, Bs);
  EPI128
  #pragma unroll
  for (int i = 0; i < 4; ++i) {
    const int rbase = m0 + wm * 64 + i * 16;   // global neighbor-row base
    const int node = rbase >> 4;
    const int cnt = cnts[node];
    #pragma unroll
    for (int j = 0; j < 4; ++j) {
      const int gc = n0 + wn * 64 + j * 16 + col;
      const float add = bu[gc] + Ct[(size_t)node * 256 + gc];
      float t[4];
      float mx = -1e30f;
      #pragma unroll
      for (int r = 0; r < 4; ++r) {
        int k = rq * 4 + r;
        t[r] = sigmoidf_(acc[i][j][r] + add);
        if (k < cnt) mx = fmaxf(mx, t[r]);
      }
      mx = fmaxf(mx, __shfl_xor(mx, 16, 64));
      mx = fmaxf(mx, __shfl_xor(mx, 32, 64));
      float ps = 0.f, cs = 0.f;
      #pragma unroll
      for (int r = 0; r < 4; ++r) {
        int k = rq * 4 + r;
        float p = (k < cnt) ? __expf(t[r] - mx) : 0.f;
        ps += p;
        cs += p * __bfloat162float(neigh[((size_t)(rbase + k)) * 256 + gc]);
      }
      ps += __shfl_xor(ps, 16, 64); ps += __shfl_xor(ps, 32, 64);
      cs += __shfl_xor(cs, 16, 64); cs += __shfl_xor(cs, 32, 64);
      if (rq == 0) con[(size_t)node * 256 + gc] = __float2bfloat16(cs / ps);
    }
  }
}

// ---- simple GEMM on 128 core: out = act(A @ Bt^T + bias). 0: f32, 1: sigmoid->bf16
template<int ACT>
__global__ __launch_bounds__(256) void k_gemm_s128(
    const bf16* __restrict__ A, const bf16* __restrict__ Bt,
    const float* __restrict__ bias, void* __restrict__ outp) {
  __shared__ bf16 As[128 * LDSQ], Bs[128 * LDSQ];
  floatx4 acc[4][4];
  gemm128_core<0, false>(A, nullptr, 256, 256, Bt, nullptr, 256, 8, acc, As, Bs);
  EPI128
  #pragma unroll
  for (int i = 0; i < 4; ++i)
    #pragma unroll
    for (int j = 0; j < 4; ++j) {
      int gc = n0 + wn * 64 + j * 16 + col;
      float b = bias[gc];
      #pragma unroll
      for (int r = 0; r < 4; ++r) {
        int gm = m0 + wm * 64 + i * 16 + rq * 4 + r;
        float v = acc[i][j][r] + b;
        if (ACT == 1) ((bf16*)outp)[(size_t)gm * 256 + gc] = __float2bfloat16(sigmoidf_(v));
        else          ((float*)outp)[(size_t)gm * 256 + gc] = v;
      }
    }
}

// ---- gate on 128 core: acc = center@Wg + con@Ug (K=512 dual); z = g*c+(1-g)*con
__global__ __launch_bounds__(256) void k_gate128(
    const bf16* __restrict__ center, const bf16* __restrict__ con,
    const bf16* __restrict__ WgT, const bf16* __restrict__ UgT,
    const float* __restrict__ bg, const float* __restrict__ bug,
    bf16* __restrict__ zb, float* __restrict__ zf) {
  __shared__ bf16 As[128 * LDSQ], Bs[128 * LDSQ];
  floatx4 acc[4][4];
  gemm128_core<0, true>(center, con, 256, 256, WgT, UgT, 256, 16, acc, As, Bs);
  EPI128
  #pragma unroll
  for (int i = 0; i < 4; ++i)
    #pragma unroll
    for (int j = 0; j < 4; ++j) {
      int gc = n0 + wn * 64 + j * 16 + col;
      float b2 = bg[gc] + bug[gc];
      #pragma unroll
      for (int r = 0; r < 4; ++r) {
        int gm = m0 + wm * 64 + i * 16 + rq * 4 + r;
        float g  = sigmoidf_(acc[i][j][r] + b2);
        float cv = __bfloat162float(center[(size_t)gm * 256 + gc]);
        float ov = __bfloat162float(con[(size_t)gm * 256 + gc]);
        float zv = g * cv + (1.f - g) * ov;
        zb[(size_t)gm * 256 + gc] = __float2bfloat16(zv);
        zf[(size_t)gm * 256 + gc] = zv;
      }
    }
}

// ---- softmax over N=128 (axis=1) fused with sent = sum(av*z)
__global__ __launch_bounds__(256) void k_rowsoftmax(
    const float* __restrict__ L, const float* __restrict__ zf, float* __restrict__ sent) {
  const int b = blockIdx.x, c = threadIdx.x;
  float m = -1e30f, s = 0.f, acc = 0.f;
  for (int n = 0; n < 128; ++n) {
    size_t idx = ((size_t)b * 128 + n) * 256 + c;
    float v = L[idx];
    if (v > m) { float sc = __expf(m - v); s *= sc; acc *= sc; m = v; }
    float p = __expf(v - m);
    s += p;
    acc += p * zf[idx];
  }
  sent[b * 256 + c] = acc / s;
}

// ---- final: log_softmax(sent @ Wc + bc). One wave per batch row.
__global__ __launch_bounds__(64) void k_final(
    const float* __restrict__ sent, const float* __restrict__ Wc,
    const float* __restrict__ bc, float* __restrict__ out) {
  const int b = blockIdx.x, l = threadIdx.x;
  float part[5] = {0.f, 0.f, 0.f, 0.f, 0.f};
  #pragma unroll
  for (int u = 0; u < 4; ++u) {
    int c = l * 4 + u;
    float sv = sent[b * 256 + c];
    #pragma unroll
    for (int j = 0; j < 5; ++j) part[j] += sv * Wc[c * 5 + j];
  }
  #pragma unroll
  for (int j = 0; j < 5; ++j)
    for (int d = 1; d < 64; d <<= 1) part[j] += __shfl_xor(part[j], d, 64);
  if (l == 0) {
    float lg[5], mx = -1e30f;
    #pragma unroll
    for (int j = 0; j < 5; ++j) { lg[j] = part[j] + bc[j]; mx = fmaxf(mx, lg[j]); }
    float ss = 0.f;
    #pragma unroll
    for (int j = 0; j < 5; ++j) ss += __expf(lg[j] - mx);
    float lse = logf(ss) + mx;
    #pragma unroll
    for (int j = 0; j < 5; ++j) out[b * 5 + j] = lg[j] - lse;
  }
}

extern "C" void kernel_launch(void* const* d_in, const int* in_sizes, int n_in,
                              void* d_out, int out_size, void* d_ws, size_t ws_size,
                              hipStream_t stream) {
  const float* x    = (const float*)d_in[0];
  const int*   cnts = (const int*)d_in[1];
  const float* Wx_w = (const float*)d_in[2];  const float* Wx_b = (const float*)d_in[3];
  const float* Wh_w = (const float*)d_in[4];  const float* Wh_b = (const float*)d_in[5];
  const float* Uh_w = (const float*)d_in[6];  const float* Uh_b = (const float*)d_in[7];
  const float* Wg_w = (const float*)d_in[8];  const float* Wg_b = (const float*)d_in[9];
  const float* Ug_w = (const float*)d_in[10]; const float* Ug_b = (const float*)d_in[11];
  const float* Wa_w = (const float*)d_in[12]; const float* Wa_b = (const float*)d_in[13];
  const float* V_w  = (const float*)d_in[14]; const float* V_b  = (const float*)d_in[15];
  const float* Wc_w = (const float*)d_in[16]; const float* Wc_b = (const float*)d_in[17];
  float* out = (float*)d_out;
  (void)in_sizes; (void)n_in; (void)out_size;

  char* ws = (char*)d_ws;
  size_t off = 0;
  auto alloc = [&](size_t bytes) -> char* {
    char* p = ws + off; off += (bytes + 255) & ~(size_t)255; return p;
  };
  bf16* WxT    = (bf16*)alloc(256 * 320 * sizeof(bf16)); // zero-padded K 300->320
  bf16* WhT    = (bf16*)alloc(256 * 256 * sizeof(bf16));
  bf16* UhT    = (bf16*)alloc(256 * 256 * sizeof(bf16));
  bf16* WgT    = (bf16*)alloc(256 * 256 * sizeof(bf16));
  bf16* UgT    = (bf16*)alloc(256 * 256 * sizeof(bf16));
  bf16* WaT    = (bf16*)alloc(256 * 256 * sizeof(bf16));
  bf16* VT     = (bf16*)alloc(256 * 256 * sizeof(bf16));
  bf16* center = (bf16*)alloc((size_t)8192 * 256 * 2);
  bf16* neigh  = (bf16*)alloc((size_t)131072 * 256 * 2);
  float* Ct    = (float*)alloc((size_t)8192 * 256 * 4);   // reused as L after attn
  bf16* con    = (bf16*)alloc((size_t)8192 * 256 * 2);
  bf16* zb     = (bf16*)alloc((size_t)8192 * 256 * 2);
  float* zf    = (float*)alloc((size_t)8192 * 256 * 4);
  bf16* S      = (bf16*)alloc((size_t)8192 * 256 * 2);
  float* sent  = (float*)alloc((size_t)64 * 256 * 4);
  float* L     = Ct;  // Ct is dead after attn; alias saves 8 MB
  if (off > ws_size) return;  // fail loudly (wrong output) rather than corrupt

  // weight prep: 7 transposes in one launch
  TransPack tp;
  tp.src[0] = Wx_w; tp.dst[0] = WxT; tp.rows[0] = 300; tp.dld[0] = 320;
  tp.src[1] = Wh_w; tp.dst[1] = WhT; tp.rows[1] = 256; tp.dld[1] = 256;
  tp.src[2] = Uh_w; tp.dst[2] = UhT; tp.rows[2] = 256; tp.dld[2] = 256;
  tp.src[3] = Wg_w; tp.dst[3] = WgT; tp.rows[3] = 256; tp.dld[3] = 256;
  tp.src[4] = Ug_w; tp.dst[4] = UgT; tp.rows[4] = 256; tp.dld[4] = 256;
  tp.src[5] = Wa_w; tp.dst[5] = WaT; tp.rows[5] = 256; tp.dld[5] = 256;
  tp.src[6] = V_w;  tp.dst[6] = VT;  tp.rows[6] = 256; tp.dld[6] = 256;
  k_transpose_all<<<dim3(320, 7), 256, 0, stream>>>(tp);

  // h = tanh(x@Wx+b) -> center(8192x256) + neigh(131072x256), bf16
  k_gemm1_128<<<dim3(1088, 2), 256, 0, stream>>>(x, WxT, Wx_b, center, neigh);
  // Ct = center@Wh + bh (fp32)
  k_gemm_s128<0><<<dim3(64, 2), 256, 0, stream>>>(center, WhT, Wh_b, Ct);
  // con = sum_k softmax_k(sigmoid(Ct + neigh@Uh + bu), mask) * neigh
  k_gemm_attn_128<<<dim3(1024, 2), 256, 0, stream>>>(neigh, UhT, Uh_b, Ct, cnts, con);
  // z = g*center + (1-g)*con, g = sigmoid(center@Wg + con@Ug + bg + bug)
  k_gate128<<<dim3(64, 2), 256, 0, stream>>>(center, con, WgT, UgT, Wg_b, Ug_b, zb, zf);
  // S = sigmoid(z@Wa + ba)
  k_gemm_s128<1><<<dim3(64, 2), 256, 0, stream>>>(zb, WaT, Wa_b, S);
  // L = S@V + bv (fp32, aliases Ct)
  k_gemm_s128<0><<<dim3(64, 2), 256, 0, stream>>>(S, VT, V_b, L);
  // sent = sum_n softmax_n(L) * z
  k_rowsoftmax<<<dim3(64), 256, 0, stream>>>(L, zf, sent);
  // out = log_softmax(sent@Wc + bc)
  k_final<<<dim3(64), 64, 0, stream>>>(sent, Wc_w, Wc_b, out);
}

// Round 12
// 473.754 us; speedup vs baseline: 1.0224x; 1.0224x over previous
//
#include <hip/hip_runtime.h>
#include <hip/hip_bf16.h>
#include <math.h>

typedef __attribute__((ext_vector_type(8))) short short8;
typedef __attribute__((ext_vector_type(4))) float floatx4;
typedef __hip_bfloat16 bf16;

#define LDSQ 40   // 128x128 core LDS stride: 80B rows -> uniform bank spread (validated r3/r11)

__device__ __forceinline__ float sigmoidf_(float v) { return 1.f / (1.f + __expf(-v)); }
// tanh via single v_exp: 1 - 2/(e^{2v}+1). |abs err| ~1e-7 (validated r11, absmax 0.0078)
__device__ __forceinline__ float tanhf_(float v) {
  float e = __expf(2.f * v);
  return 1.f - 2.f / (e + 1.f);
}
// truncation pack: lo16(hi)|hi16(lo) -> 2 bf16 in one u32 (validated r11)
__device__ __forceinline__ unsigned pk2_(float lo, float hi) {
  return (__float_as_uint(hi) & 0xFFFF0000u) | (__float_as_uint(lo) >> 16);
}

// ---------------------------------------------------------------------------
// 128x128-tile bf16 MFMA core: 256 thr = 4 waves (2x2), each wave a 64x64
// quadrant = 4x4 fragments of v_mfma_f32_16x16x32_bf16 (64 acc VGPRs).
// BK=32; per K-step: stage A+B (reg->LDS), 8 ds_read_b128 + 16 MFMA per lane.
// AMODE 0: A bf16. AMODE 1: A fp32 truncation-packed with MINIMAL live regs
// (pack each float4 pair immediately -- keeps unified VGPR+AGPR under the
// 128-reg 4-waves/SIMD boundary; r11 measured 132 regs -> 2 waves/SIMD, 30% occ).
// DUAL: K-loop spans two (A,Bt) pairs (validated pointer-switch).
// ---------------------------------------------------------------------------
template<int AMODE, bool DUAL>
__device__ __forceinline__ void gemm128_core(
    const void* A0p, const void* A1p, int lda, int kvalid,
    const bf16* B0, const bf16* B1, int ldb, int ksteps,
    floatx4 acc[4][4], bf16* As, bf16* Bs)
{
  const int tid = threadIdx.x, lane = tid & 63, wave = tid >> 6;
  const int wm = wave >> 1, wn = wave & 1;
  const int srow = tid >> 1, sc = (tid & 1) * 16;   // staging: 128 rows x 2 halves of 16
  const size_t m0 = (size_t)blockIdx.x * 128;
  const size_t n0 = (size_t)blockIdx.y * 128;
  const int half = DUAL ? (ksteps >> 1) : ksteps;
  const int fr = lane & 15, kb = lane >> 4;

  #pragma unroll
  for (int i = 0; i < 4; ++i)
    #pragma unroll
    for (int j = 0; j < 4; ++j) acc[i][j] = {0.f, 0.f, 0.f, 0.f};

  for (int kt = 0; kt < ksteps; ++kt) {
    const bool second = DUAL && (kt >= half);
    const void* Ap = second ? A1p : A0p;
    const bf16* Bp = second ? B1 : B0;
    const int kbase = (second ? (kt - half) : kt) * 32 + sc;

    if (AMODE == 1) {
      const float* Af = (const float*)Ap + (m0 + srow) * (size_t)lda + kbase;
      uint4 p0, p1;
      if (kbase + 16 <= kvalid) {
        // load one float4, pack, release -- peak live fp regs ~8 instead of 16
        float4 q0 = *(const float4*)(Af);
        p0.x = pk2_(q0.x, q0.y); p0.y = pk2_(q0.z, q0.w);
        float4 q1 = *(const float4*)(Af + 4);
        p0.z = pk2_(q1.x, q1.y); p0.w = pk2_(q1.z, q1.w);
        float4 q2 = *(const float4*)(Af + 8);
        p1.x = pk2_(q2.x, q2.y); p1.y = pk2_(q2.z, q2.w);
        float4 q3 = *(const float4*)(Af + 12);
        p1.z = pk2_(q3.x, q3.y); p1.w = pk2_(q3.z, q3.w);
      } else {
        unsigned u[16];
        #pragma unroll
        for (int e = 0; e < 16; ++e)
          u[e] = (kbase + e < kvalid) ? __float_as_uint(Af[e]) : 0u;
        p0.x = (u[1] & 0xFFFF0000u) | (u[0] >> 16);
        p0.y = (u[3] & 0xFFFF0000u) | (u[2] >> 16);
        p0.z = (u[5] & 0xFFFF0000u) | (u[4] >> 16);
        p0.w = (u[7] & 0xFFFF0000u) | (u[6] >> 16);
        p1.x = (u[9] & 0xFFFF0000u) | (u[8] >> 16);
        p1.y = (u[11] & 0xFFFF0000u) | (u[10] >> 16);
        p1.z = (u[13] & 0xFFFF0000u) | (u[12] >> 16);
        p1.w = (u[15] & 0xFFFF0000u) | (u[14] >> 16);
      }
      *(uint4*)&As[srow * LDSQ + sc]     = p0;
      *(uint4*)&As[srow * LDSQ + sc + 8] = p1;
    } else {
      const bf16* Ab = (const bf16*)Ap + (m0 + srow) * (size_t)lda + kbase;
      *(short8*)&As[srow * LDSQ + sc]     = *(const short8*)Ab;
      *(short8*)&As[srow * LDSQ + sc + 8] = *(const short8*)(Ab + 8);
    }
    {
      const bf16* Bb = Bp + (n0 + srow) * (size_t)ldb + kbase;
      *(short8*)&Bs[srow * LDSQ + sc]     = *(const short8*)Bb;
      *(short8*)&Bs[srow * LDSQ + sc + 8] = *(const short8*)(Bb + 8);
    }
    __syncthreads();

    short8 a[4], b[4];
    #pragma unroll
    for (int i = 0; i < 4; ++i)
      a[i] = *(const short8*)&As[(wm * 64 + i * 16 + fr) * LDSQ + kb * 8];
    #pragma unroll
    for (int j = 0; j < 4; ++j)
      b[j] = *(const short8*)&Bs[(wn * 64 + j * 16 + fr) * LDSQ + kb * 8];
    #pragma unroll
    for (int i = 0; i < 4; ++i)
      #pragma unroll
      for (int j = 0; j < 4; ++j)
        acc[i][j] = __builtin_amdgcn_mfma_f32_16x16x32_bf16(a[i], b[j], acc[i][j], 0, 0, 0);
    __syncthreads();
  }
}

// C/D fragment element (verified m89/m91): col = lane&15, row = (lane>>4)*4 + reg
#define EPI128 \
  const int tid = threadIdx.x, lane = tid & 63, wave = tid >> 6; \
  const int wm = wave >> 1, wn = wave & 1; \
  const int m0 = blockIdx.x * 128, n0 = blockIdx.y * 128; \
  const int rq = lane >> 4, col = lane & 15; \
  (void)m0;

// ---- all weight transposes in one launch: dst[c][r]=src[r][c], pad r to dld
struct TransPack {
  const float* src[7];
  bf16* dst[7];
  int rows[7];
  int dld[7];
};
__global__ __launch_bounds__(256) void k_transpose_all(TransPack p) {
  const int w = blockIdx.y;                 // wave-uniform -> scalar kernarg loads
  const int dld = p.dld[w];
  int idx = blockIdx.x * 256 + threadIdx.x;
  if (idx >= 256 * dld) return;
  int c = idx / dld, r = idx - c * dld;
  float v = (r < p.rows[w]) ? p.src[w][(size_t)r * 256 + c] : 0.f;
  p.dst[w][idx] = __float2bfloat16(v);
}

// ---- GEMM1: h = tanh(x @ Wx + bx) -> scatter to center/neigh. 128x128 tile.
__global__ __launch_bounds__(256, 4) void k_gemm1_128(
    const float* __restrict__ x, const bf16* __restrict__ WxT,
    const float* __restrict__ bx, bf16* __restrict__ center, bf16* __restrict__ neigh) {
  __shared__ bf16 As[128 * LDSQ], Bs[128 * LDSQ];
  floatx4 acc[4][4];
  gemm128_core<1, false>(x, nullptr, 300, 300, WxT, nullptr, 320, 10, acc, As, Bs);
  EPI128
  #pragma unroll
  for (int i = 0; i < 4; ++i)
    #pragma unroll
    for (int j = 0; j < 4; ++j) {
      int gc = n0 + wn * 64 + j * 16 + col;
      float bias = bx[gc];
      #pragma unroll
      for (int r = 0; r < 4; ++r) {
        int gm = m0 + wm * 64 + i * 16 + rq * 4 + r;
        float v = tanhf_(acc[i][j][r] + bias);
        int node = gm / 17, slot = gm - node * 17;
        bf16 bv = __float2bfloat16(v);
        if (slot == 0) center[(size_t)node * 256 + gc] = bv;
        else           neigh[((size_t)node * 16 + (slot - 1)) * 256 + gc] = bv;
      }
    }
}

// ---- attn: neigh @ Uh, fused masked softmax over K=16 + con reduce. 128x128.
// Each 16x16 C fragment = one node (16 neighbor rows = softmax axis) x 16 ch.
__global__ __launch_bounds__(256, 4) void k_gemm_attn_128(
    const bf16* __restrict__ neigh, const bf16* __restrict__ UhT,
    const float* __restrict__ bu, const float* __restrict__ Ct,
    const int* __restrict__ cnts, bf16* __restrict__ con) {
  __shared__ bf16 As[128 * LDSQ], Bs[128 * LDSQ];
  floatx4 acc[4][4];
  gemm128_core<0, false>(neigh, nullptr, 256, 256, UhT, nullptr, 256, 8, acc, As, Bs);
  EPI128
  #pragma unroll
  for (int i = 0; i < 4; ++i) {
    const int rbase = m0 + wm * 64 + i * 16;   // global neighbor-row base
    const int node = rbase >> 4;
    const int cnt = cnts[node];
    #pragma unroll
    for (int j = 0; j < 4; ++j) {
      const int gc = n0 + wn * 64 + j * 16 + col;
      const float add = bu[gc] + Ct[(size_t)node * 256 + gc];
      float t[4];
      float mx = -1e30f;
      #pragma unroll
      for (int r = 0; r < 4; ++r) {
        int k = rq * 4 + r;
        t[r] = sigmoidf_(acc[i][j][r] + add);
        if (k < cnt) mx = fmaxf(mx, t[r]);
      }
      mx = fmaxf(mx, __shfl_xor(mx, 16, 64));
      mx = fmaxf(mx, __shfl_xor(mx, 32, 64));
      float ps = 0.f, cs = 0.f;
      #pragma unroll
      for (int r = 0; r < 4; ++r) {
        int k = rq * 4 + r;
        float p = (k < cnt) ? __expf(t[r] - mx) : 0.f;
        ps += p;
        cs += p * __bfloat162float(neigh[((size_t)(rbase + k)) * 256 + gc]);
      }
      ps += __shfl_xor(ps, 16, 64); ps += __shfl_xor(ps, 32, 64);
      cs += __shfl_xor(cs, 16, 64); cs += __shfl_xor(cs, 32, 64);
      if (rq == 0) con[(size_t)node * 256 + gc] = __float2bfloat16(cs / ps);
    }
  }
}

// ---- simple GEMM on 128 core: out = act(A @ Bt^T + bias). 0: f32, 1: sigmoid->bf16
template<int ACT>
__global__ __launch_bounds__(256, 4) void k_gemm_s128(
    const bf16* __restrict__ A, const bf16* __restrict__ Bt,
    const float* __restrict__ bias, void* __restrict__ outp) {
  __shared__ bf16 As[128 * LDSQ], Bs[128 * LDSQ];
  floatx4 acc[4][4];
  gemm128_core<0, false>(A, nullptr, 256, 256, Bt, nullptr, 256, 8, acc, As, Bs);
  EPI128
  #pragma unroll
  for (int i = 0; i < 4; ++i)
    #pragma unroll
    for (int j = 0; j < 4; ++j) {
      int gc = n0 + wn * 64 + j * 16 + col;
      float b = bias[gc];
      #pragma unroll
      for (int r = 0; r < 4; ++r) {
        int gm = m0 + wm * 64 + i * 16 + rq * 4 + r;
        float v = acc[i][j][r] + b;
        if (ACT == 1) ((bf16*)outp)[(size_t)gm * 256 + gc] = __float2bfloat16(sigmoidf_(v));
        else          ((float*)outp)[(size_t)gm * 256 + gc] = v;
      }
    }
}

// ---- gate on 128 core: acc = center@Wg + con@Ug (K=512 dual); z = g*c+(1-g)*con
__global__ __launch_bounds__(256, 4) void k_gate128(
    const bf16* __restrict__ center, const bf16* __restrict__ con,
    const bf16* __restrict__ WgT, const bf16* __restrict__ UgT,
    const float* __restrict__ bg, const float* __restrict__ bug,
    bf16* __restrict__ zb, float* __restrict__ zf) {
  __shared__ bf16 As[128 * LDSQ], Bs[128 * LDSQ];
  floatx4 acc[4][4];
  gemm128_core<0, true>(center, con, 256, 256, WgT, UgT, 256, 16, acc, As, Bs);
  EPI128
  #pragma unroll
  for (int i = 0; i < 4; ++i)
    #pragma unroll
    for (int j = 0; j < 4; ++j) {
      int gc = n0 + wn * 64 + j * 16 + col;
      float b2 = bg[gc] + bug[gc];
      #pragma unroll
      for (int r = 0; r < 4; ++r) {
        int gm = m0 + wm * 64 + i * 16 + rq * 4 + r;
        float g  = sigmoidf_(acc[i][j][r] + b2);
        float cv = __bfloat162float(center[(size_t)gm * 256 + gc]);
        float ov = __bfloat162float(con[(size_t)gm * 256 + gc]);
        float zv = g * cv + (1.f - g) * ov;
        zb[(size_t)gm * 256 + gc] = __float2bfloat16(zv);
        zf[(size_t)gm * 256 + gc] = zv;
      }
    }
}

// ---- softmax over N=128 (axis=1) fused with sent = sum(av*z).
// 4-wide load batching: 8 independent loads in flight per group (latency ILP).
__global__ __launch_bounds__(256) void k_rowsoftmax(
    const float* __restrict__ L, const float* __restrict__ zf, float* __restrict__ sent) {
  const int b = blockIdx.x, c = threadIdx.x;
  float m = -1e30f, s = 0.f, acc = 0.f;
  for (int n = 0; n < 128; n += 4) {
    float v[4], z[4];
    #pragma unroll
    for (int e = 0; e < 4; ++e) {
      size_t idx = ((size_t)b * 128 + n + e) * 256 + c;
      v[e] = L[idx];
      z[e] = zf[idx];
    }
    #pragma unroll
    for (int e = 0; e < 4; ++e) {
      if (v[e] > m) { float sc = __expf(m - v[e]); s *= sc; acc *= sc; m = v[e]; }
      float p = __expf(v[e] - m);
      s += p;
      acc += p * z[e];
    }
  }
  sent[b * 256 + c] = acc / s;
}

// ---- final: log_softmax(sent @ Wc + bc). One wave per batch row.
__global__ __launch_bounds__(64) void k_final(
    const float* __restrict__ sent, const float* __restrict__ Wc,
    const float* __restrict__ bc, float* __restrict__ out) {
  const int b = blockIdx.x, l = threadIdx.x;
  float part[5] = {0.f, 0.f, 0.f, 0.f, 0.f};
  #pragma unroll
  for (int u = 0; u < 4; ++u) {
    int c = l * 4 + u;
    float sv = sent[b * 256 + c];
    #pragma unroll
    for (int j = 0; j < 5; ++j) part[j] += sv * Wc[c * 5 + j];
  }
  #pragma unroll
  for (int j = 0; j < 5; ++j)
    for (int d = 1; d < 64; d <<= 1) part[j] += __shfl_xor(part[j], d, 64);
  if (l == 0) {
    float lg[5], mx = -1e30f;
    #pragma unroll
    for (int j = 0; j < 5; ++j) { lg[j] = part[j] + bc[j]; mx = fmaxf(mx, lg[j]); }
    float ss = 0.f;
    #pragma unroll
    for (int j = 0; j < 5; ++j) ss += __expf(lg[j] - mx);
    float lse = logf(ss) + mx;
    #pragma unroll
    for (int j = 0; j < 5; ++j) out[b * 5 + j] = lg[j] - lse;
  }
}

extern "C" void kernel_launch(void* const* d_in, const int* in_sizes, int n_in,
                              void* d_out, int out_size, void* d_ws, size_t ws_size,
                              hipStream_t stream) {
  const float* x    = (const float*)d_in[0];
  const int*   cnts = (const int*)d_in[1];
  const float* Wx_w = (const float*)d_in[2];  const float* Wx_b = (const float*)d_in[3];
  const float* Wh_w = (const float*)d_in[4];  const float* Wh_b = (const float*)d_in[5];
  const float* Uh_w = (const float*)d_in[6];  const float* Uh_b = (const float*)d_in[7];
  const float* Wg_w = (const float*)d_in[8];  const float* Wg_b = (const float*)d_in[9];
  const float* Ug_w = (const float*)d_in[10]; const float* Ug_b = (const float*)d_in[11];
  const float* Wa_w = (const float*)d_in[12]; const float* Wa_b = (const float*)d_in[13];
  const float* V_w  = (const float*)d_in[14]; const float* V_b  = (const float*)d_in[15];
  const float* Wc_w = (const float*)d_in[16]; const float* Wc_b = (const float*)d_in[17];
  float* out = (float*)d_out;
  (void)in_sizes; (void)n_in; (void)out_size;

  char* ws = (char*)d_ws;
  size_t off = 0;
  auto alloc = [&](size_t bytes) -> char* {
    char* p = ws + off; off += (bytes + 255) & ~(size_t)255; return p;
  };
  bf16* WxT    = (bf16*)alloc(256 * 320 * sizeof(bf16)); // zero-padded K 300->320
  bf16* WhT    = (bf16*)alloc(256 * 256 * sizeof(bf16));
  bf16* UhT    = (bf16*)alloc(256 * 256 * sizeof(bf16));
  bf16* WgT    = (bf16*)alloc(256 * 256 * sizeof(bf16));
  bf16* UgT    = (bf16*)alloc(256 * 256 * sizeof(bf16));
  bf16* WaT    = (bf16*)alloc(256 * 256 * sizeof(bf16));
  bf16* VT     = (bf16*)alloc(256 * 256 * sizeof(bf16));
  bf16* center = (bf16*)alloc((size_t)8192 * 256 * 2);
  bf16* neigh  = (bf16*)alloc((size_t)131072 * 256 * 2);
  float* Ct    = (float*)alloc((size_t)8192 * 256 * 4);   // reused as L after attn
  bf16* con    = (bf16*)alloc((size_t)8192 * 256 * 2);
  bf16* zb     = (bf16*)alloc((size_t)8192 * 256 * 2);
  float* zf    = (float*)alloc((size_t)8192 * 256 * 4);
  bf16* S      = (bf16*)alloc((size_t)8192 * 256 * 2);
  float* sent  = (float*)alloc((size_t)64 * 256 * 4);
  float* L     = Ct;  // Ct is dead after attn; alias saves 8 MB
  if (off > ws_size) return;  // fail loudly (wrong output) rather than corrupt

  // weight prep: 7 transposes in one launch
  TransPack tp;
  tp.src[0] = Wx_w; tp.dst[0] = WxT; tp.rows[0] = 300; tp.dld[0] = 320;
  tp.src[1] = Wh_w; tp.dst[1] = WhT; tp.rows[1] = 256; tp.dld[1] = 256;
  tp.src[2] = Uh_w; tp.dst[2] = UhT; tp.rows[2] = 256; tp.dld[2] = 256;
  tp.src[3] = Wg_w; tp.dst[3] = WgT; tp.rows[3] = 256; tp.dld[3] = 256;
  tp.src[4] = Ug_w; tp.dst[4] = UgT; tp.rows[4] = 256; tp.dld[4] = 256;
  tp.src[5] = Wa_w; tp.dst[5] = WaT; tp.rows[5] = 256; tp.dld[5] = 256;
  tp.src[6] = V_w;  tp.dst[6] = VT;  tp.rows[6] = 256; tp.dld[6] = 256;
  k_transpose_all<<<dim3(320, 7), 256, 0, stream>>>(tp);

  // h = tanh(x@Wx+b) -> center(8192x256) + neigh(131072x256), bf16
  k_gemm1_128<<<dim3(1088, 2), 256, 0, stream>>>(x, WxT, Wx_b, center, neigh);
  // Ct = center@Wh + bh (fp32)
  k_gemm_s128<0><<<dim3(64, 2), 256, 0, stream>>>(center, WhT, Wh_b, Ct);
  // con = sum_k softmax_k(sigmoid(Ct + neigh@Uh + bu), mask) * neigh
  k_gemm_attn_128<<<dim3(1024, 2), 256, 0, stream>>>(neigh, UhT, Uh_b, Ct, cnts, con);
  // z = g*center + (1-g)*con, g = sigmoid(center@Wg + con@Ug + bg + bug)
  k_gate128<<<dim3(64, 2), 256, 0, stream>>>(center, con, WgT, UgT, Wg_b, Ug_b, zb, zf);
  // S = sigmoid(z@Wa + ba)
  k_gemm_s128<1><<<dim3(64, 2), 256, 0, stream>>>(zb, WaT, Wa_b, S);
  // L = S@V + bv (fp32, aliases Ct)
  k_gemm_s128<0><<<dim3(64, 2), 256, 0, stream>>>(S, VT, V_b, L);
  // sent = sum_n softmax_n(L) * z
  k_rowsoftmax<<<dim3(64), 256, 0, stream>>>(L, zf, sent);
  // out = log_softmax(sent@Wc + bc)
  k_final<<<dim3(64), 64, 0, stream>>>(sent, Wc_w, Wc_b, out);
}